// Round 6
// baseline (46.014 us; speedup 1.0000x reference)
//
#include <hip/hip_runtime.h>

typedef __attribute__((ext_vector_type(8))) short short8;
typedef __attribute__((ext_vector_type(4))) float f32x4;

#define NROWS 32768        // B*H*W
#define NELEM 262144       // B*C*H*W
#define KCB   8192
#define ROWS_PB 64
#define NWAVE 16           // k-waves per block; each scans KCB/16 = 512 entries

// round-to-nearest-even fp32 -> bf16 (finite values only)
static __device__ __forceinline__ short to_bf16(float x) {
    unsigned u = __float_as_uint(x);
    unsigned r = (u + 0x7FFFu + ((u >> 16) & 1u)) >> 16;
    return (short)r;
}

// Prep: pack codebook entries as 16 bf16 [e0..e7, -0.5*||e||^2, 0...]; zero loss.
__global__ __launch_bounds__(256) void vq_prep(
    const float* __restrict__ cb, short8* __restrict__ cbb, float* __restrict__ out)
{
    int k = blockIdx.x * 256 + threadIdx.x;
    if (k == 0) out[NELEM] = 0.0f;
    const float4* p = (const float4*)(cb + (size_t)k * 8);
    float4 a = p[0], b = p[1];
    float h = -0.5f * (a.x*a.x + a.y*a.y + a.z*a.z + a.w*a.w
                     + b.x*b.x + b.y*b.y + b.z*b.z + b.w*b.w);
    short8 lo = { to_bf16(a.x), to_bf16(a.y), to_bf16(a.z), to_bf16(a.w),
                  to_bf16(b.x), to_bf16(b.y), to_bf16(b.z), to_bf16(b.w) };
    short8 hi = { to_bf16(h), 0, 0, 0, 0, 0, 0, 0 };
    cbb[2 * k]     = lo;
    cbb[2 * k + 1] = hi;
}

// Main: 512 blocks x 1024 thr (16 k-waves), 64 rows/block -> 8 waves/SIMD.
// Wave w scans private 512-entry k-slice, direct global(L2)->VGPR, depth-2
// pair prefetch. Argmax = v_and_or pack (score|inv-idx) + v_max3 pairing.
__global__ __launch_bounds__(1024, 8) void vq_main(
    const float* __restrict__ z, const float* __restrict__ cb,
    const short8* __restrict__ cbb, float* __restrict__ out)
{
    __shared__ float sbest[NWAVE][ROWS_PB];
    __shared__ float lsum[NWAVE];

    const int tid  = threadIdx.x;
    const int lane = tid & 63;
    const int w    = tid >> 6;        // k-wave 0..15
    const int col  = lane & 15;
    const int g    = lane >> 4;

    const int row0 = blockIdx.x * ROWS_PB;

    // ---- A fragments: 4 row-tiles of 16; k-slots 0..7 = channels, 8 = 1.0 ----
    short8 af[4];
    #pragma unroll
    for (int f = 0; f < 4; ++f) {
        short8 v = {0, 0, 0, 0, 0, 0, 0, 0};
        if (g == 0) {
            const int row = row0 + f * 16 + col;
            const float* zp = z + (size_t)(row >> 12) * 32768 + (row & 4095);
            v[0] = to_bf16(zp[0]);     v[1] = to_bf16(zp[4096]);
            v[2] = to_bf16(zp[8192]);  v[3] = to_bf16(zp[12288]);
            v[4] = to_bf16(zp[16384]); v[5] = to_bf16(zp[20480]);
            v[6] = to_bf16(zp[24576]); v[7] = to_bf16(zp[28672]);
        } else if (g == 1) {
            v[0] = (short)0x3F80;      // bf16(1.0) pairs with -0.5||e||^2
        }
        af[f] = v;
    }

    const int kbase = w * (KCB / NWAVE);         // 512-entry slice
    const char* bpc = (const char*)cbb + (size_t)(kbase + col) * 32
                                       + (size_t)(g & 1) * 16;

    float best[4][4];
    #pragma unroll
    for (int f = 0; f < 4; ++f)
        #pragma unroll
        for (int r = 0; r < 4; ++r)
            best[f][r] = __uint_as_float(0xFF800000u);   // -inf

    const unsigned inv0 = (unsigned)(8191 - (kbase + col));
    const unsigned MSK = 0xFFFFE000u;
    const f32x4 zacc = {0.f, 0.f, 0.f, 0.f};

#define LDT(T) (*(const short8*)(bpc + (size_t)(T) * 512))

    auto comp2 = [&](short8 b0, short8 b1, unsigned iv0) {
        const unsigned iv1 = iv0 - 16u;
        #pragma unroll
        for (int f = 0; f < 4; ++f) {
            f32x4 a0 = __builtin_amdgcn_mfma_f32_16x16x32_bf16(af[f], b0, zacc, 0, 0, 0);
            f32x4 a1 = __builtin_amdgcn_mfma_f32_16x16x32_bf16(af[f], b1, zacc, 0, 0, 0);
            #pragma unroll
            for (int r = 0; r < 4; ++r) {
                float p0 = __uint_as_float((__float_as_uint(a0[r]) & MSK) | iv0);  // v_and_or_b32
                float p1 = __uint_as_float((__float_as_uint(a1[r]) & MSK) | iv1);
                best[f][r] = fmaxf(fmaxf(p0, p1), best[f][r]);                     // v_max3_f32
            }
        }
    };

    // ---- 32 tiles = 16 pairs, depth-2 (1 pair) register prefetch, branchless wrap ----
    short8 c0 = LDT(0);
    short8 c1 = LDT(1);
    #pragma unroll 4
    for (int tt = 0; tt < 16; ++tt) {
        short8 n0 = LDT((2 * tt + 2) & 31);
        short8 n1 = LDT((2 * tt + 3) & 31);
        comp2(c0, c1, inv0 - (unsigned)(tt * 32));
        c0 = n0; c1 = n1;
    }

    // ---- cross-lane max within each 16-lane col group ----
    #pragma unroll
    for (int d = 1; d < 16; d <<= 1)
        #pragma unroll
        for (int f = 0; f < 4; ++f)
            #pragma unroll
            for (int r = 0; r < 4; ++r)
                best[f][r] = fmaxf(best[f][r], __shfl_xor(best[f][r], d));

    if (col == 0) {
        #pragma unroll
        for (int f = 0; f < 4; ++f)
            #pragma unroll
            for (int r = 0; r < 4; ++r)
                sbest[w][f * 16 + g * 4 + r] = best[f][r];   // row = g*4+r of tile f
    }
    __syncthreads();

    // ---- emit: 64 rows x 8 ch, one elem/thread (first 512 threads) ----
    float sq = 0.0f;
    if (tid < 512) {
        const int pos = tid & 63;
        const int ch  = tid >> 6;
        float m = sbest[0][pos];
        #pragma unroll
        for (int kw = 1; kw < NWAVE; ++kw) m = fmaxf(m, sbest[kw][pos]);
        const int k = 8191 - (int)(__float_as_uint(m) & 8191u);

        const int n = row0 + pos;
        const size_t o = ((size_t)(n >> 12)) * 32768 + (size_t)ch * 4096 + (size_t)(n & 4095);
        float ev = cb[(size_t)k * 8 + ch];
        float zz = z[o];
        out[o] = ev;
        float dd = ev - zz;
        sq = dd * dd;
    }
    #pragma unroll
    for (int off = 32; off > 0; off >>= 1) sq += __shfl_down(sq, off);
    if (lane == 0) lsum[w] = sq;
    __syncthreads();
    if (tid == 0) {
        float s = 0.f;
        #pragma unroll
        for (int kw = 0; kw < NWAVE; ++kw) s += lsum[kw];
        atomicAdd(out + NELEM, s * (1.25f / (float)NELEM));
    }
}

extern "C" void kernel_launch(void* const* d_in, const int* in_sizes, int n_in,
                              void* d_out, int out_size, void* d_ws, size_t ws_size,
                              hipStream_t stream)
{
    const float* z  = (const float*)d_in[0];   // [8, 8, 64, 64] fp32
    const float* cb = (const float*)d_in[1];   // [8192, 8] fp32
    float* out = (float*)d_out;                // 262144 z_q + 1 loss
    short8* cbb = (short8*)d_ws;               // 256 KB packed codebook

    vq_prep<<<KCB / 256, 256, 0, stream>>>(cb, cbb, out);
    vq_main<<<NROWS / ROWS_PB, 1024, 0, stream>>>(z, cb, cbb, out);
}

// Round 7
// 38.869 us; speedup vs baseline: 1.1838x; 1.1838x over previous
//
#include <hip/hip_runtime.h>

typedef __attribute__((ext_vector_type(8))) short short8;
typedef __attribute__((ext_vector_type(4))) float f32x4;

#define NROWS 32768        // B*H*W
#define NELEM 262144       // B*C*H*W
#define KCB   8192
#define ROWS_PB 32         // rows per block (2 row-tiles of 16)
#define NWAVE 8            // k-waves per block; each scans KCB/8 = 1024 entries

// round-to-nearest-even fp32 -> bf16 (finite values only)
static __device__ __forceinline__ short to_bf16(float x) {
    unsigned u = __float_as_uint(x);
    unsigned r = (u + 0x7FFFu + ((u >> 16) & 1u)) >> 16;
    return (short)r;
}

// Prep: pack codebook entries as 16 bf16 [e0..e7, -0.5*||e||^2, 0...]; zero loss.
__global__ __launch_bounds__(256) void vq_prep(
    const float* __restrict__ cb, short8* __restrict__ cbb, float* __restrict__ out)
{
    int k = blockIdx.x * 256 + threadIdx.x;
    if (k == 0) out[NELEM] = 0.0f;
    const float4* p = (const float4*)(cb + (size_t)k * 8);
    float4 a = p[0], b = p[1];
    float h = -0.5f * (a.x*a.x + a.y*a.y + a.z*a.z + a.w*a.w
                     + b.x*b.x + b.y*b.y + b.z*b.z + b.w*b.w);
    short8 lo = { to_bf16(a.x), to_bf16(a.y), to_bf16(a.z), to_bf16(a.w),
                  to_bf16(b.x), to_bf16(b.y), to_bf16(b.z), to_bf16(b.w) };
    short8 hi = { to_bf16(h), 0, 0, 0, 0, 0, 0, 0 };
    cbb[2 * k]     = lo;
    cbb[2 * k + 1] = hi;
}

// Main: 1024 blocks x 512 thr (8 k-waves), 32 rows/block -> 8192 waves
// = 8 waves/SIMD, 4 blocks/CU. Per-wave state ~46 VGPR (fits the 64 cap
// WITHOUT spilling, unlike round 6's F=4). Direct global(L2)->VGPR B-loads,
// depth-2 pair prefetch. Argmax = v_and_or pack (score|inv-idx) + v_max3.
__global__ __launch_bounds__(512, 8) void vq_main(
    const float* __restrict__ z, const float* __restrict__ cb,
    const short8* __restrict__ cbb, float* __restrict__ out)
{
    __shared__ float sbest[NWAVE][ROWS_PB];
    __shared__ float lsum[NWAVE];

    const int tid  = threadIdx.x;
    const int lane = tid & 63;
    const int w    = tid >> 6;        // k-wave 0..7
    const int col  = lane & 15;
    const int g    = lane >> 4;

    const int row0 = blockIdx.x * ROWS_PB;

    // ---- A fragments: 2 row-tiles of 16; k-slots 0..7 = channels, 8 = 1.0 ----
    short8 af0 = {0,0,0,0,0,0,0,0}, af1 = af0;
    if (g == 0) {
        const int r0 = row0 + col;
        const float* zp0 = z + (size_t)(r0 >> 12) * 32768 + (r0 & 4095);
        af0[0] = to_bf16(zp0[0]);     af0[1] = to_bf16(zp0[4096]);
        af0[2] = to_bf16(zp0[8192]);  af0[3] = to_bf16(zp0[12288]);
        af0[4] = to_bf16(zp0[16384]); af0[5] = to_bf16(zp0[20480]);
        af0[6] = to_bf16(zp0[24576]); af0[7] = to_bf16(zp0[28672]);
        const int r1 = row0 + 16 + col;
        const float* zp1 = z + (size_t)(r1 >> 12) * 32768 + (r1 & 4095);
        af1[0] = to_bf16(zp1[0]);     af1[1] = to_bf16(zp1[4096]);
        af1[2] = to_bf16(zp1[8192]);  af1[3] = to_bf16(zp1[12288]);
        af1[4] = to_bf16(zp1[16384]); af1[5] = to_bf16(zp1[20480]);
        af1[6] = to_bf16(zp1[24576]); af1[7] = to_bf16(zp1[28672]);
    } else if (g == 1) {
        af0[0] = (short)0x3F80;        // bf16(1.0) pairs with -0.5||e||^2
        af1[0] = (short)0x3F80;
    }

    const int kbase = w * (KCB / NWAVE);         // 1024-entry slice
    const char* bpc = (const char*)cbb + (size_t)(kbase + col) * 32
                                       + (size_t)(g & 1) * 16;

    float best[2][4];
    #pragma unroll
    for (int f = 0; f < 2; ++f)
        #pragma unroll
        for (int r = 0; r < 4; ++r)
            best[f][r] = __uint_as_float(0xFF800000u);   // -inf

    const unsigned inv0 = (unsigned)(8191 - (kbase + col));
    const unsigned MSK = 0xFFFFE000u;
    const f32x4 zacc = {0.f, 0.f, 0.f, 0.f};

#define LDT(T) (*(const short8*)(bpc + (size_t)(T) * 512))

    // ---- 64 tiles = 32 pairs, depth-2 (1 pair) prefetch, branchless wrap ----
    short8 c0 = LDT(0);
    short8 c1 = LDT(1);
    #pragma unroll 4
    for (int tt = 0; tt < 32; ++tt) {
        short8 n0 = LDT((2 * tt + 2) & 63);
        short8 n1 = LDT((2 * tt + 3) & 63);
        const unsigned iv0 = inv0 - (unsigned)(tt * 32);
        const unsigned iv1 = iv0 - 16u;
        f32x4 a00 = __builtin_amdgcn_mfma_f32_16x16x32_bf16(af0, c0, zacc, 0, 0, 0);
        f32x4 a01 = __builtin_amdgcn_mfma_f32_16x16x32_bf16(af0, c1, zacc, 0, 0, 0);
        f32x4 a10 = __builtin_amdgcn_mfma_f32_16x16x32_bf16(af1, c0, zacc, 0, 0, 0);
        f32x4 a11 = __builtin_amdgcn_mfma_f32_16x16x32_bf16(af1, c1, zacc, 0, 0, 0);
        #pragma unroll
        for (int r = 0; r < 4; ++r) {
            float p00 = __uint_as_float((__float_as_uint(a00[r]) & MSK) | iv0);
            float p01 = __uint_as_float((__float_as_uint(a01[r]) & MSK) | iv1);
            best[0][r] = fmaxf(fmaxf(p00, p01), best[0][r]);     // v_max3_f32
            float p10 = __uint_as_float((__float_as_uint(a10[r]) & MSK) | iv0);
            float p11 = __uint_as_float((__float_as_uint(a11[r]) & MSK) | iv1);
            best[1][r] = fmaxf(fmaxf(p10, p11), best[1][r]);
        }
        c0 = n0; c1 = n1;
    }

    // ---- cross-lane max within each 16-lane col group ----
    #pragma unroll
    for (int d = 1; d < 16; d <<= 1)
        #pragma unroll
        for (int f = 0; f < 2; ++f)
            #pragma unroll
            for (int r = 0; r < 4; ++r)
                best[f][r] = fmaxf(best[f][r], __shfl_xor(best[f][r], d));

    if (col == 0) {
        #pragma unroll
        for (int f = 0; f < 2; ++f)
            #pragma unroll
            for (int r = 0; r < 4; ++r)
                sbest[w][f * 16 + g * 4 + r] = best[f][r];   // row = g*4+r of tile f
    }
    __syncthreads();

    // ---- emit: 32 rows x 8 ch, one elem/thread (first 256 threads) ----
    float sq = 0.0f;
    if (tid < 256) {
        const int pos = tid & 31;
        const int ch  = tid >> 5;
        float m = sbest[0][pos];
        #pragma unroll
        for (int kw = 1; kw < NWAVE; ++kw) m = fmaxf(m, sbest[kw][pos]);
        const int k = 8191 - (int)(__float_as_uint(m) & 8191u);

        const int n = row0 + pos;
        const size_t o = ((size_t)(n >> 12)) * 32768 + (size_t)ch * 4096 + (size_t)(n & 4095);
        float ev = cb[(size_t)k * 8 + ch];
        float zz = z[o];
        out[o] = ev;
        float dd = ev - zz;
        sq = dd * dd;
    }
    #pragma unroll
    for (int off = 32; off > 0; off >>= 1) sq += __shfl_down(sq, off);
    if (lane == 0) lsum[w] = sq;
    __syncthreads();
    if (tid == 0) {
        float s = 0.f;
        #pragma unroll
        for (int kw = 0; kw < NWAVE; ++kw) s += lsum[kw];
        atomicAdd(out + NELEM, s * (1.25f / (float)NELEM));
    }
}

extern "C" void kernel_launch(void* const* d_in, const int* in_sizes, int n_in,
                              void* d_out, int out_size, void* d_ws, size_t ws_size,
                              hipStream_t stream)
{
    const float* z  = (const float*)d_in[0];   // [8, 8, 64, 64] fp32
    const float* cb = (const float*)d_in[1];   // [8192, 8] fp32
    float* out = (float*)d_out;                // 262144 z_q + 1 loss
    short8* cbb = (short8*)d_ws;               // 256 KB packed codebook

    vq_prep<<<KCB / 256, 256, 0, stream>>>(cb, cbb, out);
    vq_main<<<NROWS / ROWS_PB, 512, 0, stream>>>(z, cb, cbb, out);
}